// Round 1
// baseline (456.346 us; speedup 1.0000x reference)
//
#include <hip/hip_runtime.h>
#include <hip/hip_bf16.h>
#include <stdint.h>

#define ALPHA 0.2f

typedef __attribute__((ext_vector_type(4))) float f32x4;
typedef __attribute__((ext_vector_type(8))) __bf16 bf16x8;
typedef __attribute__((ext_vector_type(8))) unsigned short u16x8;
typedef __attribute__((ext_vector_type(4))) unsigned short u16x4;

static __device__ __forceinline__ unsigned short f2bf(float f) {
  unsigned u = __builtin_bit_cast(unsigned, f);
  u += 0x7FFFu + ((u >> 16) & 1u);   // RNE
  return (unsigned short)(u >> 16);
}
static __device__ __forceinline__ float bf2f(unsigned short h) {
  unsigned u = ((unsigned)h) << 16;
  return __builtin_bit_cast(float, u);
}
// async global->LDS, 16B per lane. LDS dest must be wave-uniform base + lane*16.
static __device__ __forceinline__ void gl_lds16(const void* g, void* lds) {
  __builtin_amdgcn_global_load_lds(
      (const __attribute__((address_space(1))) unsigned int*)g,
      (__attribute__((address_space(3))) unsigned int*)lds, 16, 0, 0);
}

// ---------------- adj -> bitmask (2 MB) ----------------
__global__ void k_pack_bits(const int* __restrict__ adj, unsigned int* __restrict__ bits) {
  int gid  = blockIdx.x * 4 + (threadIdx.x >> 6);  // wave id
  int lane = threadIdx.x & 63;
  int i   = gid >> 6;    // row
  int w64 = gid & 63;    // 64-bit word within row
  int j = (w64 << 6) | lane;
  int v = adj[(long)i * 4096 + j];
  unsigned long long m = __ballot(v != 0);
  if (lane == 0) {
    bits[i * 128 + 2 * w64]     = (unsigned int)m;
    bits[i * 128 + 2 * w64 + 1] = (unsigned int)(m >> 32);
  }
}

// ---------------- fp32 -> bf16 cast (x) ----------------
__global__ void k_cast_bf16(const float* __restrict__ in, unsigned short* __restrict__ out, int n8) {
  int t = blockIdx.x * blockDim.x + threadIdx.x;
  if (t >= n8) return;
  const f32x4* p = (const f32x4*)(in + (long)t * 8);
  f32x4 a = p[0], b = p[1];
  u16x8 o;
#pragma unroll
  for (int k = 0; k < 4; ++k) { o[k] = f2bf(a[k]); o[k + 4] = f2bf(b[k]); }
  *(u16x8*)(out + (long)t * 8) = o;
}

// ---------------- transpose + cast: in [K][N] fp32 -> out [N][K] bf16 ----------------
__global__ void k_transpose_bf16(const float* __restrict__ in, unsigned short* __restrict__ out,
                                 int K, int N) {
  __shared__ float t[32][33];
  long bs = (long)K * N;
  const float* inb = in + blockIdx.z * bs;
  unsigned short* outb = out + blockIdx.z * bs;
  int k0 = blockIdx.x * 32, n0 = blockIdx.y * 32;
  int tx = threadIdx.x & 31, ty = threadIdx.x >> 5;  // ty 0..7
#pragma unroll
  for (int it = 0; it < 4; ++it)
    t[ty + it * 8][tx] = inb[(long)(k0 + ty + it * 8) * N + n0 + tx];
  __syncthreads();
#pragma unroll
  for (int it = 0; it < 4; ++it)
    outb[(long)(n0 + ty + it * 8) * K + k0 + tx] = f2bf(t[tx][ty + it * 8]);
}

// ---------------- Wh GEMM: A[4096,K]bf16 @ BT[f][K]bf16 -> whT[f][4096] bf16 ----------------
// block 256 thr (4 waves), tile MT=64 x NT=128, K-step 32
__global__ void __launch_bounds__(256, 4)
k_gemm_wh(const unsigned short* __restrict__ A, const unsigned short* __restrict__ BT,
          unsigned short* __restrict__ whT, int K) {
  __shared__ unsigned short As[64 * 32];
  __shared__ unsigned short Bs[128 * 32];
  const int tid = threadIdx.x, lane = tid & 63, wid = tid >> 6;
  const int q = lane >> 4, l15 = lane & 15;
  const int i0 = blockIdx.x * 64;
  const int fbase = blockIdx.z * 256 + blockIdx.y * 128;  // row in BT / whT
  const int wm = wid >> 1, wn = wid & 1;
  f32x4 acc[2][4] = {};
  const unsigned short* aRow = A + (long)(i0 + (tid >> 2)) * K + (tid & 3) * 8;
  for (int kk = 0; kk < K; kk += 32) {
    __syncthreads();
    gl_lds16(aRow + kk, (char*)As + tid * 16);  // A: 64x32 = 256 chunks
#pragma unroll
    for (int half = 0; half < 2; ++half) {      // B: 128x32 = 512 chunks
      int cid = half * 256 + tid;
      gl_lds16(BT + (long)(fbase + (cid >> 2)) * K + kk + (cid & 3) * 8,
               (char*)Bs + cid * 16);
    }
    __syncthreads();
    bf16x8 af[2], bfr[4];
#pragma unroll
    for (int mi = 0; mi < 2; ++mi)
      af[mi] = *(const bf16x8*)&As[(wm * 32 + mi * 16 + l15) * 32 + q * 8];
#pragma unroll
    for (int ni = 0; ni < 4; ++ni)
      bfr[ni] = *(const bf16x8*)&Bs[(wn * 64 + ni * 16 + l15) * 32 + q * 8];
#pragma unroll
    for (int mi = 0; mi < 2; ++mi)
#pragma unroll
      for (int ni = 0; ni < 4; ++ni)
        acc[mi][ni] = __builtin_amdgcn_mfma_f32_16x16x32_bf16(af[mi], bfr[ni], acc[mi][ni], 0, 0, 0);
  }
  // write transposed: whT[f][i]; C/D row (=i) is reg -> 4 consecutive i -> 8B stores
#pragma unroll
  for (int mi = 0; mi < 2; ++mi)
#pragma unroll
    for (int ni = 0; ni < 4; ++ni) {
      int ig = i0 + wm * 32 + mi * 16 + q * 4;
      int fg = fbase + wn * 64 + ni * 16 + l15;
      u16x4 v;
#pragma unroll
      for (int r = 0; r < 4; ++r) v[r] = f2bf(acc[mi][ni][r]);
      *(u16x4*)&whT[(long)fg * 4096 + ig] = v;
    }
}

// ---------------- src/dst: per row i, dot(Wh[i,:], a) halves ----------------
__global__ void k_rowdot(const unsigned short* __restrict__ whT, const float* __restrict__ a,
                         float* __restrict__ srcv, float* __restrict__ dstv, int aStride) {
  int i = blockIdx.x * 256 + threadIdx.x;
  int h = blockIdx.y;
  const unsigned short* w = whT + (long)h * 256 * 4096 + i;
  const float* ah = a + h * aStride;
  float s = 0.f, d = 0.f;
#pragma unroll 8
  for (int f = 0; f < 256; ++f) {
    float v = bf2f(w[(long)f * 4096]);
    s += v * ah[f];
    d += v * ah[256 + f];
  }
  srcv[h * 4096 + i] = s;
  dstv[h * 4096 + i] = d;
}

// ---------------- softmax stats: s_i = m_i + ln(sum exp(e - m)) ----------------
template <int H>
__global__ void __launch_bounds__(256)
k_stats(const unsigned int* __restrict__ bits, const float* __restrict__ srcv,
        const float* __restrict__ dstv, float* __restrict__ sstat) {
  int i = blockIdx.x;
  int tid = threadIdx.x, lane = tid & 63, wid = tid >> 6;
  float srcr[H], m[H], ev[16 * H];
#pragma unroll
  for (int h = 0; h < H; ++h) { srcr[h] = srcv[h * 4096 + i]; m[h] = -1e30f; }
  for (int k = 0; k < 16; ++k) {
    int j = tid + k * 256;
    unsigned w = bits[i * 128 + (j >> 5)];
    bool bit = (w >> (j & 31)) & 1u;
#pragma unroll
    for (int h = 0; h < H; ++h) {
      float e = srcr[h] + dstv[h * 4096 + j];
      e = fmaxf(e, ALPHA * e);           // LeakyReLU
      e = bit ? e : -1e30f;
      ev[k * H + h] = e;
      m[h] = fmaxf(m[h], e);
    }
  }
  __shared__ float red[H][4];
#pragma unroll
  for (int h = 0; h < H; ++h)
#pragma unroll
    for (int off = 32; off; off >>= 1) m[h] = fmaxf(m[h], __shfl_xor(m[h], off));
  if (lane == 0)
#pragma unroll
    for (int h = 0; h < H; ++h) red[h][wid] = m[h];
  __syncthreads();
#pragma unroll
  for (int h = 0; h < H; ++h) m[h] = fmaxf(fmaxf(red[h][0], red[h][1]), fmaxf(red[h][2], red[h][3]));
  float l[H];
#pragma unroll
  for (int h = 0; h < H; ++h) l[h] = 0.f;
  for (int k = 0; k < 16; ++k)
#pragma unroll
    for (int h = 0; h < H; ++h) l[h] += __expf(ev[k * H + h] - m[h]);  // masked -> exp(-1e30)=0
  __syncthreads();
#pragma unroll
  for (int h = 0; h < H; ++h)
#pragma unroll
    for (int off = 32; off; off >>= 1) l[h] += __shfl_xor(l[h], off);
  if (lane == 0)
#pragma unroll
    for (int h = 0; h < H; ++h) red[h][wid] = l[h];
  __syncthreads();
  if (tid == 0)
#pragma unroll
    for (int h = 0; h < H; ++h)
      sstat[h * 4096 + i] = m[h] + __logf(red[h][0] + red[h][1] + red[h][2] + red[h][3]);
}

// ---------------- fused attention GEMM: O = softmax(mask(lrelu(src+dst))) @ Wh ----------------
// block 512 thr (8 waves), tile MT x 128, K-step 32. P computed in-regs -> LDS bf16.
// MODE 0: out bf16 + ELU into h1[4096,1024] at col head*256+f0; MODE 1: fp32, no ELU, [4096,256]
template <int MT, int MODE>
__global__ void __launch_bounds__(512, 4)
k_attn(const unsigned short* __restrict__ whT, const unsigned int* __restrict__ bits,
       const float* __restrict__ srcv, const float* __restrict__ dstv,
       const float* __restrict__ sstat, void* __restrict__ outp) {
  __shared__ unsigned short Bs[128 * 32];
  __shared__ unsigned short Ps[MT * 32];
  const int tid = threadIdx.x, lane = tid & 63, wid = tid >> 6;
  const int q = lane >> 4, l15 = lane & 15;
  const int i0 = blockIdx.x * MT;
  const int head = blockIdx.y;
  const int f0 = blockIdx.z * 128;
  const int wm = wid >> 2, wn = wid & 3;
  constexpr int MF = MT / 32;  // m-frags per wave
  f32x4 acc[MF][2] = {};
  // P-writer per-lane row constants (wave w owns P rows [w*16, w*16+16))
  const int prow_l = wid * 16 + l15;
  const bool pw = prow_l < MT;
  float src_r = 0.f, s_r = 0.f;
  const unsigned int* brow = bits;
  if (pw) {
    src_r = srcv[head * 4096 + i0 + prow_l];
    s_r   = sstat[head * 4096 + i0 + prow_l];
    brow  = bits + (long)(i0 + prow_l) * 128;
  }
  const float* dsth = dstv + head * 4096;
  const unsigned short* wrow = whT + (long)(head * 256 + f0 + (tid >> 2)) * 4096 + (tid & 3) * 8;

  for (int j0 = 0; j0 < 4096; j0 += 32) {
    __syncthreads();
    gl_lds16(wrow + j0, (char*)Bs + tid * 16);  // B tile: 128 f x 32 j
    if (pw) {
      int jb = j0 + q * 8;
      f32x4 d0 = *(const f32x4*)(dsth + jb);
      f32x4 d1 = *(const f32x4*)(dsth + jb + 4);
      unsigned byte = brow[j0 >> 5] >> (q * 8);
      u16x8 p;
#pragma unroll
      for (int jj = 0; jj < 8; ++jj) {
        float dj = (jj < 4) ? d0[jj] : d1[jj - 4];
        float e = src_r + dj;
        e = fmaxf(e, ALPHA * e);
        float pe = ((byte >> jj) & 1u) ? __expf(e - s_r) : 0.f;
        p[jj] = f2bf(pe);
      }
      *(u16x8*)&Ps[prow_l * 32 + q * 8] = p;
    }
    __syncthreads();
    bf16x8 bfr[2];
#pragma unroll
    for (int ni = 0; ni < 2; ++ni)
      bfr[ni] = *(const bf16x8*)&Bs[(wn * 32 + ni * 16 + l15) * 32 + q * 8];
#pragma unroll
    for (int mi = 0; mi < MF; ++mi) {
      bf16x8 af = *(const bf16x8*)&Ps[(wm * (MT / 2) + mi * 16 + l15) * 32 + q * 8];
#pragma unroll
      for (int ni = 0; ni < 2; ++ni)
        acc[mi][ni] = __builtin_amdgcn_mfma_f32_16x16x32_bf16(af, bfr[ni], acc[mi][ni], 0, 0, 0);
    }
  }
#pragma unroll
  for (int mi = 0; mi < MF; ++mi)
#pragma unroll
    for (int ni = 0; ni < 2; ++ni) {
      int iloc = wm * (MT / 2) + mi * 16 + q * 4;
      int floc = wn * 32 + ni * 16 + l15;
#pragma unroll
      for (int r = 0; r < 4; ++r) {
        float v = acc[mi][ni][r];
        long row = i0 + iloc + r;
        if (MODE == 0) {
          v = v > 0.f ? v : (__expf(v) - 1.f);  // ELU
          ((unsigned short*)outp)[row * 1024 + head * 256 + f0 + floc] = f2bf(v);
        } else {
          ((float*)outp)[row * 256 + f0 + floc] = v;
        }
      }
    }
}

extern "C" void kernel_launch(void* const* d_in, const int* in_sizes, int n_in,
                              void* d_out, int out_size, void* d_ws, size_t ws_size,
                              hipStream_t stream) {
  const float* x  = (const float*)d_in[0];
  const int* adj  = (const int*)d_in[1];
  const float* W1 = (const float*)d_in[2];
  const float* a1 = (const float*)d_in[3];
  const float* W2 = (const float*)d_in[4];
  const float* a2 = (const float*)d_in[5];

  char* ws = (char*)d_ws;
  size_t off = 0;
  auto alloc = [&](size_t bytes) {
    void* p = ws + off;
    off = (off + bytes + 255) & ~(size_t)255;
    return p;
  };
  unsigned int*   bits = (unsigned int*)  alloc((size_t)4096 * 128 * 4);   //  2 MB
  unsigned short* xb   = (unsigned short*)alloc((size_t)4096 * 512 * 2);   //  4 MB
  unsigned short* w1t  = (unsigned short*)alloc((size_t)4 * 256 * 512 * 2);//  1 MB
  unsigned short* w2t  = (unsigned short*)alloc((size_t)256 * 1024 * 2);   // .5 MB
  unsigned short* whT1 = (unsigned short*)alloc((size_t)1024 * 4096 * 2);  //  8 MB
  unsigned short* h1   = (unsigned short*)alloc((size_t)4096 * 1024 * 2);  //  8 MB
  unsigned short* whT2 = (unsigned short*)alloc((size_t)256 * 4096 * 2);   //  2 MB
  float* src1 = (float*)alloc(4 * 4096 * 4);
  float* dst1 = (float*)alloc(4 * 4096 * 4);
  float* s1   = (float*)alloc(4 * 4096 * 4);
  float* src2 = (float*)alloc(4096 * 4);
  float* dst2 = (float*)alloc(4096 * 4);
  float* s2   = (float*)alloc(4096 * 4);

  k_pack_bits<<<dim3(65536), dim3(256), 0, stream>>>(adj, bits);
  k_cast_bf16<<<dim3(1024), dim3(256), 0, stream>>>(x, xb, 262144);
  k_transpose_bf16<<<dim3(16, 8, 4), dim3(256), 0, stream>>>(W1, w1t, 512, 256);
  k_transpose_bf16<<<dim3(32, 8, 1), dim3(256), 0, stream>>>(W2, w2t, 1024, 256);

  // layer 1
  k_gemm_wh<<<dim3(64, 2, 4), dim3(256), 0, stream>>>(xb, w1t, whT1, 512);
  k_rowdot<<<dim3(16, 4), dim3(256), 0, stream>>>(whT1, a1, src1, dst1, 512);
  k_stats<4><<<dim3(4096), dim3(256), 0, stream>>>(bits, src1, dst1, s1);
  k_attn<128, 0><<<dim3(32, 4, 2), dim3(512), 0, stream>>>(whT1, bits, src1, dst1, s1, h1);

  // layer 2
  k_gemm_wh<<<dim3(64, 2, 1), dim3(256), 0, stream>>>(h1, w2t, whT2, 1024);
  k_rowdot<<<dim3(16, 1), dim3(256), 0, stream>>>(whT2, a2, src2, dst2, 512);
  k_stats<1><<<dim3(4096), dim3(256), 0, stream>>>(bits, src2, dst2, s2);
  k_attn<64, 1><<<dim3(64, 1, 2), dim3(512), 0, stream>>>(whT2, bits, src2, dst2, s2, d_out);
}

// Round 2
// 296.361 us; speedup vs baseline: 1.5398x; 1.5398x over previous
//
#include <hip/hip_runtime.h>
#include <hip/hip_bf16.h>
#include <stdint.h>

#define ALPHA 0.2f

typedef __attribute__((ext_vector_type(4))) float f32x4;
typedef __attribute__((ext_vector_type(8))) __bf16 bf16x8;
typedef __attribute__((ext_vector_type(8))) unsigned short u16x8;
typedef __attribute__((ext_vector_type(4))) unsigned short u16x4;

static __device__ __forceinline__ unsigned short f2bf(float f) {
  unsigned u = __builtin_bit_cast(unsigned, f);
  u += 0x7FFFu + ((u >> 16) & 1u);   // RNE
  return (unsigned short)(u >> 16);
}
static __device__ __forceinline__ float bf2f(unsigned short h) {
  unsigned u = ((unsigned)h) << 16;
  return __builtin_bit_cast(float, u);
}
// async global->LDS, 16B per lane. LDS dest must be wave-uniform base + lane*16.
static __device__ __forceinline__ void gl_lds16(const void* g, void* lds) {
  __builtin_amdgcn_global_load_lds(
      (const __attribute__((address_space(1))) unsigned int*)g,
      (__attribute__((address_space(3))) unsigned int*)lds, 16, 0, 0);
}

// ---------------- adj -> bitmask (2 MB) ----------------
__global__ void k_pack_bits(const int* __restrict__ adj, unsigned int* __restrict__ bits) {
  int gid  = blockIdx.x * 4 + (threadIdx.x >> 6);  // wave id
  int lane = threadIdx.x & 63;
  int i   = gid >> 6;    // row
  int w64 = gid & 63;    // 64-bit word within row
  int j = (w64 << 6) | lane;
  int v = adj[(long)i * 4096 + j];
  unsigned long long m = __ballot(v != 0);
  if (lane == 0) {
    bits[i * 128 + 2 * w64]     = (unsigned int)m;
    bits[i * 128 + 2 * w64 + 1] = (unsigned int)(m >> 32);
  }
}

// ---------------- fp32 -> bf16 cast (x) ----------------
__global__ void k_cast_bf16(const float* __restrict__ in, unsigned short* __restrict__ out, int n8) {
  int t = blockIdx.x * blockDim.x + threadIdx.x;
  if (t >= n8) return;
  const f32x4* p = (const f32x4*)(in + (long)t * 8);
  f32x4 a = p[0], b = p[1];
  u16x8 o;
#pragma unroll
  for (int k = 0; k < 4; ++k) { o[k] = f2bf(a[k]); o[k + 4] = f2bf(b[k]); }
  *(u16x8*)(out + (long)t * 8) = o;
}

// ---------------- transpose + cast: in [K][N] fp32 -> out [N][K] bf16 ----------------
__global__ void k_transpose_bf16(const float* __restrict__ in, unsigned short* __restrict__ out,
                                 int K, int N) {
  __shared__ float t[32][33];
  long bs = (long)K * N;
  const float* inb = in + blockIdx.z * bs;
  unsigned short* outb = out + blockIdx.z * bs;
  int k0 = blockIdx.x * 32, n0 = blockIdx.y * 32;
  int tx = threadIdx.x & 31, ty = threadIdx.x >> 5;  // ty 0..7
#pragma unroll
  for (int it = 0; it < 4; ++it)
    t[ty + it * 8][tx] = inb[(long)(k0 + ty + it * 8) * N + n0 + tx];
  __syncthreads();
#pragma unroll
  for (int it = 0; it < 4; ++it)
    outb[(long)(n0 + ty + it * 8) * K + k0 + tx] = f2bf(t[tx][ty + it * 8]);
}

// ---------------- Wh GEMM: A[4096,K]bf16 @ BT[f][K]bf16 -> whT[f][4096] bf16 ----------------
__global__ void __launch_bounds__(256, 4)
k_gemm_wh(const unsigned short* __restrict__ A, const unsigned short* __restrict__ BT,
          unsigned short* __restrict__ whT, int K) {
  __shared__ unsigned short As[64 * 32];
  __shared__ unsigned short Bs[128 * 32];
  const int tid = threadIdx.x, lane = tid & 63, wid = tid >> 6;
  const int q = lane >> 4, l15 = lane & 15;
  const int i0 = blockIdx.x * 64;
  const int fbase = blockIdx.z * 256 + blockIdx.y * 128;  // row in BT / whT
  const int wm = wid >> 1, wn = wid & 1;
  f32x4 acc[2][4] = {};
  const unsigned short* aRow = A + (long)(i0 + (tid >> 2)) * K + (tid & 3) * 8;
  for (int kk = 0; kk < K; kk += 32) {
    __syncthreads();
    gl_lds16(aRow + kk, (char*)As + tid * 16);
#pragma unroll
    for (int half = 0; half < 2; ++half) {
      int cid = half * 256 + tid;
      gl_lds16(BT + (long)(fbase + (cid >> 2)) * K + kk + (cid & 3) * 8,
               (char*)Bs + cid * 16);
    }
    __syncthreads();
    bf16x8 af[2], bfr[4];
#pragma unroll
    for (int mi = 0; mi < 2; ++mi)
      af[mi] = *(const bf16x8*)&As[(wm * 32 + mi * 16 + l15) * 32 + q * 8];
#pragma unroll
    for (int ni = 0; ni < 4; ++ni)
      bfr[ni] = *(const bf16x8*)&Bs[(wn * 64 + ni * 16 + l15) * 32 + q * 8];
#pragma unroll
    for (int mi = 0; mi < 2; ++mi)
#pragma unroll
      for (int ni = 0; ni < 4; ++ni)
        acc[mi][ni] = __builtin_amdgcn_mfma_f32_16x16x32_bf16(af[mi], bfr[ni], acc[mi][ni], 0, 0, 0);
  }
#pragma unroll
  for (int mi = 0; mi < 2; ++mi)
#pragma unroll
    for (int ni = 0; ni < 4; ++ni) {
      int ig = i0 + wm * 32 + mi * 16 + q * 4;
      int fg = fbase + wn * 64 + ni * 16 + l15;
      u16x4 v;
#pragma unroll
      for (int r = 0; r < 4; ++r) v[r] = f2bf(acc[mi][ni][r]);
      *(u16x4*)&whT[(long)fg * 4096 + ig] = v;
    }
}

// ---------------- wa = W @ a halves: one wave per input row ----------------
// W [rows][F] fp32, a [heads][2F] (headK rows per head). out [(h*2+v)][headK]
__global__ void k_wa(const float* __restrict__ W, const float* __restrict__ a,
                     float* __restrict__ wa, int headK, int F) {
  int w = (blockIdx.x * blockDim.x + threadIdx.x) >> 6;  // global row
  int lane = threadIdx.x & 63;
  int h = w / headK, fl = w % headK;
  const float* row = W + (size_t)w * F;
  const float* ah = a + (size_t)h * 2 * F;
  float s0 = 0.f, s1 = 0.f;
  for (int fo = lane; fo < F; fo += 64) {
    float wv = row[fo];
    s0 += wv * ah[fo];
    s1 += wv * ah[F + fo];
  }
#pragma unroll
  for (int off = 32; off; off >>= 1) {
    s0 += __shfl_xor(s0, off);
    s1 += __shfl_xor(s1, off);
  }
  if (lane == 0) {
    wa[(size_t)(h * 2 + 0) * headK + fl] = s0;
    wa[(size_t)(h * 2 + 1) * headK + fl] = s1;
  }
}

// ---------------- matvec layer1: src/dst[h][i] = x[i,:] . wa[h*2+v] ----------------
__global__ void __launch_bounds__(256) k_matvec1(const unsigned short* __restrict__ xb,
                                                 const float* __restrict__ wa,
                                                 float* __restrict__ srcv, float* __restrict__ dstv) {
  int lane = threadIdx.x & 63, wid = threadIdx.x >> 6;
  float wv[8][8];
#pragma unroll
  for (int v = 0; v < 8; ++v)
#pragma unroll
    for (int j = 0; j < 8; ++j) wv[v][j] = wa[v * 512 + lane * 8 + j];
  int base = (blockIdx.x * 4 + wid) * 16;
  for (int rr = 0; rr < 16; ++rr) {
    int i = base + rr;
    u16x8 xv = *(const u16x8*)(xb + (size_t)i * 512 + lane * 8);
    float xf[8];
#pragma unroll
    for (int j = 0; j < 8; ++j) xf[j] = bf2f(xv[j]);
    float s[8] = {};
#pragma unroll
    for (int v = 0; v < 8; ++v)
#pragma unroll
      for (int j = 0; j < 8; ++j) s[v] += xf[j] * wv[v][j];
#pragma unroll
    for (int v = 0; v < 8; ++v)
#pragma unroll
      for (int off = 32; off; off >>= 1) s[v] += __shfl_xor(s[v], off);
    if (lane == 0) {
#pragma unroll
      for (int h = 0; h < 4; ++h) {
        srcv[h * 4096 + i] = s[h * 2];
        dstv[h * 4096 + i] = s[h * 2 + 1];
      }
    }
  }
}

// ---------------- matvec layer2: src/dst[i] = h1[i,:] . wa2[v] ----------------
__global__ void __launch_bounds__(256) k_matvec2(const unsigned short* __restrict__ h1,
                                                 const float* __restrict__ wa,
                                                 float* __restrict__ srcv, float* __restrict__ dstv) {
  int lane = threadIdx.x & 63, wid = threadIdx.x >> 6;
  float wv[2][16];
#pragma unroll
  for (int v = 0; v < 2; ++v)
#pragma unroll
    for (int j = 0; j < 16; ++j) wv[v][j] = wa[v * 1024 + lane * 16 + j];
  int base = (blockIdx.x * 4 + wid) * 16;
  for (int rr = 0; rr < 16; ++rr) {
    int i = base + rr;
    u16x8 x0 = *(const u16x8*)(h1 + (size_t)i * 1024 + lane * 16);
    u16x8 x1 = *(const u16x8*)(h1 + (size_t)i * 1024 + lane * 16 + 8);
    float s0 = 0.f, s1 = 0.f;
#pragma unroll
    for (int j = 0; j < 8; ++j) {
      float a0 = bf2f(x0[j]), a1 = bf2f(x1[j]);
      s0 += a0 * wv[0][j] + a1 * wv[0][j + 8];
      s1 += a0 * wv[1][j] + a1 * wv[1][j + 8];
    }
#pragma unroll
    for (int off = 32; off; off >>= 1) {
      s0 += __shfl_xor(s0, off);
      s1 += __shfl_xor(s1, off);
    }
    if (lane == 0) { srcv[i] = s0; dstv[i] = s1; }
  }
}

// ---------------- dmax[h] = max_j dst[h][j] ----------------
__global__ void k_dmax(const float* __restrict__ dstv, float* __restrict__ dmax) {
  int h = blockIdx.x, t = threadIdx.x;
  float m = -1e30f;
  for (int k = t; k < 4096; k += 256) m = fmaxf(m, dstv[h * 4096 + k]);
#pragma unroll
  for (int off = 32; off; off >>= 1) m = fmaxf(m, __shfl_xor(m, off));
  __shared__ float r[4];
  if ((t & 63) == 0) r[t >> 6] = m;
  __syncthreads();
  if (t == 0) dmax[h] = fmaxf(fmaxf(r[0], r[1]), fmaxf(r[2], r[3]));
}

// ---------------- fused attention GEMM, j-split, fixed-shift softmax ----------------
// O_part = exp(mask(lrelu(src+dst)) - m_i) @ WhT^T, l_part = row sums.
// block 256 (4 waves): 64 rows x 256 f, j-step 64; grid = 64 tiles * H * JS (1-D),
// bid&7 = (head,js) group -> same group lands on one XCD (%8 heuristic).
template <int JS, int H, int OC>
__global__ void __launch_bounds__(256, 2)
k_attn2(const unsigned short* __restrict__ whT, const unsigned int* __restrict__ bits,
        const float* __restrict__ srcv, const float* __restrict__ dstv,
        const float* __restrict__ dmaxv, float* __restrict__ Opart, float* __restrict__ Lpart) {
  static_assert(H * JS == 8, "group size must be 8");
  __shared__ unsigned short Bs[256 * 64];  // [f][64k], k-chunks XOR-swizzled
  __shared__ unsigned short Ps[64 * 72];   // [row][64k + 8 pad]
  __shared__ float Lred[4][64];
  const int tid = threadIdx.x, lane = tid & 63, wid = tid >> 6;
  const int q = lane >> 4, l15 = lane & 15;
  const int bid = blockIdx.x;
  const int g = bid & 7;
  const int head = g & (H - 1);
  const int js = g / H;
  const int i0 = (bid >> 3) * 64;
  const int jbase = js * (4096 / JS);
  constexpr int JSTEPS = (4096 / JS) / 64;

  const float* srcp = srcv + head * 4096;
  const float* dstp = dstv + head * 4096;
  const unsigned short* wh_head = whT + (size_t)head * 256 * 4096;

  const int prow = tid & 63, kq = tid >> 6;
  float src_r = srcp[i0 + prow];
  float m_r;
  { float xm = src_r + dmaxv[head]; m_r = fmaxf(xm, ALPHA * xm); }
  const unsigned int* brow = bits + (size_t)(i0 + prow) * 128;
  float lsum = 0.f;
  f32x4 acc[4][4] = {};

  for (int jstep = 0; jstep < JSTEPS; ++jstep) {
    int j0 = jbase + jstep * 64;
    __syncthreads();
    // stage B: 256 f x 64 k = 32 KB, XOR-swizzled 16B chunks (slot = c ^ (f&7))
#pragma unroll
    for (int it = 0; it < 8; ++it) {
      int cid = it * 256 + tid;
      int row = cid >> 3, slot = cid & 7;
      int c = slot ^ (row & 7);
      gl_lds16(wh_head + (size_t)row * 4096 + j0 + c * 8, (char*)Bs + cid * 16);
    }
    // P-gen: thread (prow, kq) covers 16 j at j0 + kq*16
    {
      int jw = j0 + kq * 16;
      f32x4 dz[4];
#pragma unroll
      for (int c4 = 0; c4 < 4; ++c4) dz[c4] = *(const f32x4*)(dstp + jw + c4 * 4);
      unsigned wb = (brow[(j0 >> 5) + (kq >> 1)] >> ((kq & 1) * 16)) & 0xFFFFu;
#pragma unroll
      for (int c8 = 0; c8 < 2; ++c8) {
        u16x8 pv;
#pragma unroll
        for (int jj = 0; jj < 8; ++jj) {
          float dj = dz[c8 * 2 + (jj >> 2)][jj & 3];
          float e = src_r + dj;
          e = fmaxf(e, ALPHA * e);
          float pe = ((wb >> (c8 * 8 + jj)) & 1u) ? __expf(e - m_r) : 0.f;
          lsum += pe;
          pv[jj] = f2bf(pe);
        }
        *(u16x8*)&Ps[prow * 72 + kq * 16 + c8 * 8] = pv;
      }
    }
    __syncthreads();
#pragma unroll
    for (int s = 0; s < 2; ++s) {
      bf16x8 af[4], bfr[4];
#pragma unroll
      for (int mi = 0; mi < 4; ++mi)
        af[mi] = *(const bf16x8*)&Ps[(mi * 16 + l15) * 72 + s * 32 + q * 8];
#pragma unroll
      for (int ni = 0; ni < 4; ++ni) {
        int f = wid * 64 + ni * 16 + l15;
        int slot = (s * 4 + q) ^ (l15 & 7);
        bfr[ni] = *(const bf16x8*)&Bs[f * 64 + slot * 8];
      }
#pragma unroll
      for (int mi = 0; mi < 4; ++mi)
#pragma unroll
        for (int ni = 0; ni < 4; ++ni)
          acc[mi][ni] = __builtin_amdgcn_mfma_f32_16x16x32_bf16(af[mi], bfr[ni], acc[mi][ni], 0, 0, 0);
    }
  }
  // epilogue: row-sum partials + unnormalized O partials
  __syncthreads();
  Lred[kq][prow] = lsum;
  __syncthreads();
  if (tid < 64)
    Lpart[(size_t)(js * H + head) * 4096 + i0 + tid] =
        Lred[0][tid] + Lred[1][tid] + Lred[2][tid] + Lred[3][tid];
  float* Ob = Opart + (size_t)js * 4096 * OC + head * 256;
#pragma unroll
  for (int mi = 0; mi < 4; ++mi)
#pragma unroll
    for (int ni = 0; ni < 4; ++ni) {
      int i = i0 + mi * 16 + q * 4;
      int col = wid * 64 + ni * 16 + l15;
#pragma unroll
      for (int r = 0; r < 4; ++r)
        Ob[(size_t)(i + r) * OC + col] = acc[mi][ni][r];
    }
}

// ---------------- combine layer1: h1 = ELU((Op0+Op1)/l) as bf16 ----------------
__global__ void __launch_bounds__(256) k_comb1(const float* __restrict__ Op,
                                               const float* __restrict__ Lp,
                                               unsigned short* __restrict__ h1) {
  int gidx = blockIdx.x * 256 + threadIdx.x;  // 1M threads, 4 cols each
  int i = gidx >> 8, c0 = (gidx & 255) * 4;
  int h = c0 >> 8;
  float l = Lp[h * 4096 + i] + Lp[(4 + h) * 4096 + i];
  float inv = 1.f / l;
  f32x4 p0 = *(const f32x4*)(Op + (size_t)i * 1024 + c0);
  f32x4 p1 = *(const f32x4*)(Op + (size_t)4096 * 1024 + (size_t)i * 1024 + c0);
  u16x4 o;
#pragma unroll
  for (int r = 0; r < 4; ++r) {
    float v = (p0[r] + p1[r]) * inv;
    v = v > 0.f ? v : (__expf(v) - 1.f);
    o[r] = f2bf(v);
  }
  *(u16x4*)(h1 + (size_t)i * 1024 + c0) = o;
}

// ---------------- combine layer2: out = (sum Op_js)/l, fp32 ----------------
__global__ void __launch_bounds__(256) k_comb2(const float* __restrict__ Op,
                                               const float* __restrict__ Lp,
                                               float* __restrict__ out) {
  int gidx = blockIdx.x * 256 + threadIdx.x;  // 262144 threads, 4 cols each
  int i = gidx >> 6, c0 = (gidx & 63) * 4;
  float l = 0.f;
#pragma unroll
  for (int js = 0; js < 8; ++js) l += Lp[js * 4096 + i];
  f32x4 s = {0.f, 0.f, 0.f, 0.f};
#pragma unroll
  for (int js = 0; js < 8; ++js)
    s += *(const f32x4*)(Op + (size_t)js * 4096 * 256 + (size_t)i * 256 + c0);
  float inv = 1.f / l;
  f32x4 o;
#pragma unroll
  for (int r = 0; r < 4; ++r) o[r] = s[r] * inv;
  *(f32x4*)(out + (size_t)i * 256 + c0) = o;
}

extern "C" void kernel_launch(void* const* d_in, const int* in_sizes, int n_in,
                              void* d_out, int out_size, void* d_ws, size_t ws_size,
                              hipStream_t stream) {
  const float* x  = (const float*)d_in[0];
  const int* adj  = (const int*)d_in[1];
  const float* W1 = (const float*)d_in[2];
  const float* a1 = (const float*)d_in[3];
  const float* W2 = (const float*)d_in[4];
  const float* a2 = (const float*)d_in[5];

  char* ws = (char*)d_ws;
  size_t off = 0;
  auto alloc = [&](size_t bytes) {
    void* p = ws + off;
    off = (off + bytes + 255) & ~(size_t)255;
    return p;
  };
  unsigned int*   bits = (unsigned int*)  alloc((size_t)4096 * 128 * 4);    //  2 MB
  unsigned short* xb   = (unsigned short*)alloc((size_t)4096 * 512 * 2);    //  4 MB
  unsigned short* w1t  = (unsigned short*)alloc((size_t)4 * 256 * 512 * 2); //  1 MB
  unsigned short* w2t  = (unsigned short*)alloc((size_t)256 * 1024 * 2);    // .5 MB
  unsigned short* whT1 = (unsigned short*)alloc((size_t)1024 * 4096 * 2);   //  8 MB
  unsigned short* h1   = (unsigned short*)alloc((size_t)4096 * 1024 * 2);   //  8 MB
  unsigned short* whT2 = (unsigned short*)alloc((size_t)256 * 4096 * 2);    //  2 MB
  float* wa1  = (float*)alloc((size_t)8 * 512 * 4);
  float* wa2  = (float*)alloc((size_t)2 * 1024 * 4);
  float* src1 = (float*)alloc(4 * 4096 * 4);
  float* dst1 = (float*)alloc(4 * 4096 * 4);
  float* src2 = (float*)alloc(4096 * 4);
  float* dst2 = (float*)alloc(4096 * 4);
  float* dmax1 = (float*)alloc(4 * 4);
  float* dmax2 = (float*)alloc(4);
  float* Lp1  = (float*)alloc((size_t)8 * 4096 * 4);
  float* Lp2  = (float*)alloc((size_t)8 * 4096 * 4);
  float* Opart = (float*)alloc((size_t)2 * 4096 * 1024 * 4);  // 32 MB, reused by layer 2

  // prep
  k_pack_bits<<<dim3(65536), dim3(256), 0, stream>>>(adj, bits);
  k_cast_bf16<<<dim3(1024), dim3(256), 0, stream>>>(x, xb, 262144);
  k_transpose_bf16<<<dim3(16, 8, 4), dim3(256), 0, stream>>>(W1, w1t, 512, 256);
  k_transpose_bf16<<<dim3(32, 8, 1), dim3(256), 0, stream>>>(W2, w2t, 1024, 256);
  k_wa<<<dim3(512), dim3(256), 0, stream>>>(W1, a1, wa1, 512, 256);
  k_wa<<<dim3(256), dim3(256), 0, stream>>>(W2, a2, wa2, 1024, 256);

  // layer 1
  k_matvec1<<<dim3(64), dim3(256), 0, stream>>>(xb, wa1, src1, dst1);
  k_dmax<<<dim3(4), dim3(256), 0, stream>>>(dst1, dmax1);
  k_gemm_wh<<<dim3(64, 2, 4), dim3(256), 0, stream>>>(xb, w1t, whT1, 512);
  k_attn2<2, 4, 1024><<<dim3(512), dim3(256), 0, stream>>>(whT1, bits, src1, dst1, dmax1, Opart, Lp1);
  k_comb1<<<dim3(4096), dim3(256), 0, stream>>>(Opart, Lp1, h1);

  // layer 2
  k_matvec2<<<dim3(64), dim3(256), 0, stream>>>(h1, wa2, src2, dst2);
  k_dmax<<<dim3(1), dim3(256), 0, stream>>>(dst2, dmax2);
  k_gemm_wh<<<dim3(64, 2, 1), dim3(256), 0, stream>>>(h1, w2t, whT2, 1024);
  k_attn2<8, 1, 256><<<dim3(512), dim3(256), 0, stream>>>(whT2, bits, src2, dst2, dmax2, Opart, Lp2);
  k_comb2<<<dim3(1024), dim3(256), 0, stream>>>(Opart, Lp2, (float*)d_out);
}